// Round 12
// baseline (266.350 us; speedup 1.0000x reference)
//
#include <hip/hip_runtime.h>
#include <hip/hip_fp16.h>
#include <math.h>

static constexpr int N = 100000;
static constexpr int SHIFT = 7;                        // 128 nodes / bucket
static constexpr int BUCKN = 1 << SHIFT;               // 128
static constexpr int NBUCK = (N + BUCKN - 1) >> SHIFT; // 782
static constexpr int CHUNK = 16384;                    // edges per partition block
static constexpr int STRIDE = 5120;                    // per-bucket col capacity (16 sigma)
static constexpr int COLCAP = NBUCK * STRIDE;

// ---------------- init per-bucket cursors ----------------
__global__ __launch_bounds__(1024) void k_init(int* __restrict__ gcur) {
    int b = threadIdx.x;
    if (b < NBUCK) gcur[b] = b * STRIDE;
}

// ---------------- partition edges into fixed-stride bucket regions ----------------
// 1024 threads, NO LDS stash (re-read dst/src: sequential + L2-hot; round-10 vs
// round-11 A/B showed the regression came from short runs, not re-reads).
// CHUNK=16384 -> ~21-edge (~84 B) runs -> line-sized writes. LDS 6.4 KB -> high occupancy.
__global__ __launch_bounds__(1024) void k_part(const int* __restrict__ src,
                                               const int* __restrict__ dst,
                                               int* __restrict__ gcur,
                                               int* __restrict__ col, int E) {
    __shared__ int hl[NBUCK];
    __shared__ int cur[NBUCK];
    const int t = threadIdx.x, b = blockIdx.x;
    if (t < NBUCK) hl[t] = 0;    // 1024 >= NBUCK=782: single-shot OK
    __syncthreads();
    const int e0 = b * CHUNK;
    const int m = min(CHUNK, E - e0);
    for (int i = t; i < m; i += 1024) atomicAdd(&hl[dst[e0 + i] >> SHIFT], 1);
    __syncthreads();
    if (t < NBUCK) cur[t] = atomicAdd(&gcur[t], hl[t]);   // reserve run
    __syncthreads();
    for (int i = t; i < m; i += 1024) {
        int d = dst[e0 + i];
        int pos = atomicAdd(&cur[d >> SHIFT], 1);
        pos = min(max(pos, 0), COLCAP - 1);               // safety clamp (no-op)
        col[pos] = (src[e0 + i] & 0x1FFFF) | ((d & (BUCKN - 1)) << 17);
    }
}

// ---------------- in-bucket counting sort -> per-node CSR (in place) ----------------
__global__ __launch_bounds__(1024) void k_sort(const int* __restrict__ gcur,
                                               int* __restrict__ col,
                                               int* __restrict__ deg,
                                               int* __restrict__ row_start) {
    __shared__ int es[STRIDE];
    __shared__ int cnt[BUCKN];
    __shared__ int cur[BUCKN];
    const int t = threadIdx.x, buck = blockIdx.x;
    const int s0 = buck * STRIDE;
    int n = gcur[buck] - s0;
    n = max(0, min(n, STRIDE));
    if (t < BUCKN) cnt[t] = 0;
    __syncthreads();
    for (int i = t; i < n; i += 1024) {
        int p = col[s0 + i];
        es[i] = p;
        atomicAdd(&cnt[(p >> 17) & (BUCKN - 1)], 1);
    }
    __syncthreads();
    if (t < BUCKN) cur[t] = cnt[t];
    __syncthreads();
    for (int off = 1; off < BUCKN; off <<= 1) {
        int v = (t < BUCKN && t >= off) ? cur[t - off] : 0;
        __syncthreads();
        if (t < BUCKN) cur[t] += v;
        __syncthreads();
    }
    if (t < BUCKN) {
        int excl = cur[t] - cnt[t];
        int node = buck * BUCKN + t;
        if (node < N) {
            deg[node] = cnt[t];
            row_start[node] = s0 + excl;
        }
        cur[t] = excl;
    }
    __syncthreads();
    for (int i = t; i < n; i += 1024) {
        int p = es[i];
        int pos = atomicAdd(&cur[(p >> 17) & (BUCKN - 1)], 1);
        pos = min(max(pos, 0), STRIDE - 1);
        col[s0 + pos] = p & 0x1FFFF;
    }
}

// ---------------- layer 1 transform: g1h = fp16( dis * (x @ W1^T) ) ----------------
__global__ __launch_bounds__(256) void k_xw1(
        const float* __restrict__ x, const float* __restrict__ W1,
        const int* __restrict__ deg, __half* __restrict__ g1h) {
    __shared__ float4 wtv[32 * 33];   // [kb][j] quad of W1[j][4kb..4kb+3], pad 33
    __shared__ float4 xsv[1024];      // 32 nodes x 32 k-quads
    const int t = threadIdx.x;
    const float4* W1v = (const float4*)W1;
    for (int idx = t; idx < 1024; idx += 256) {
        int j = idx >> 5, kb = idx & 31;
        wtv[kb * 33 + j] = W1v[idx];
    }
    const float4* x4 = (const float4*)x + (size_t)blockIdx.x * 1024;
    for (int idx = t; idx < 1024; idx += 256) xsv[idx] = x4[idx];
    __syncthreads();

    const int j = t & 31, ng = t >> 5;
    float a0 = 0.f, a1 = 0.f, a2 = 0.f, a3 = 0.f;
#pragma unroll 4
    for (int kb = 0; kb < 32; ++kb) {
        float4 w = wtv[kb * 33 + j];
        float4 x0 = xsv[(4 * ng + 0) * 32 + kb];
        float4 x1 = xsv[(4 * ng + 1) * 32 + kb];
        float4 x2 = xsv[(4 * ng + 2) * 32 + kb];
        float4 x3 = xsv[(4 * ng + 3) * 32 + kb];
        a0 = fmaf(w.x, x0.x, fmaf(w.y, x0.y, fmaf(w.z, x0.z, fmaf(w.w, x0.w, a0))));
        a1 = fmaf(w.x, x1.x, fmaf(w.y, x1.y, fmaf(w.z, x1.z, fmaf(w.w, x1.w, a1))));
        a2 = fmaf(w.x, x2.x, fmaf(w.y, x2.y, fmaf(w.z, x2.z, fmaf(w.w, x2.w, a2))));
        a3 = fmaf(w.x, x3.x, fmaf(w.y, x3.y, fmaf(w.z, x3.z, fmaf(w.w, x3.w, a3))));
    }
    const int nb = blockIdx.x * 32 + 4 * ng;
    g1h[(nb + 0) * 32 + j] = __float2half(a0 * rsqrtf((float)(deg[nb + 0] + 1)));
    g1h[(nb + 1) * 32 + j] = __float2half(a1 * rsqrtf((float)(deg[nb + 1] + 1)));
    g1h[(nb + 2) * 32 + j] = __float2half(a2 * rsqrtf((float)(deg[nb + 2] + 1)));
    g1h[(nb + 3) * 32 + j] = __float2half(a3 * rsqrtf((float)(deg[nb + 3] + 1)));
}

// ---------------- gather layer 1 + FUSED layer-2 transform ----------------
__global__ __launch_bounds__(256) void k_gather1(
        const int* __restrict__ row_start, const int* __restrict__ deg,
        const int* __restrict__ col, const __half* __restrict__ g1h,
        const float* __restrict__ b1, const float* __restrict__ W2,
        __half* __restrict__ g2h) {
    __shared__ float h1s[64 * 33];   // 8.4 KB, pad 33
    __shared__ float w2t[32 * 17];   // W2 transposed [k][j], pad 17
    const int t = threadIdx.x;
    for (int idx = t; idx < 512; idx += 256) {
        int j = idx >> 5, k = idx & 31;
        w2t[k * 17 + j] = W2[idx];
    }
    const int lane = t & 63, w = t >> 6;
    const int q = lane & 3;                      // feature octet
    const int nloc = w * 16 + (lane >> 2);
    const int node = blockIdx.x * 64 + nloc;
    const int nc = node < N ? node : N - 1;
    const int rs = row_start[nc];
    const int ne = (node < N) ? deg[nc] : 0;
    const uint4* g1v = (const uint4*)g1h;

    float acc[8];
    {
        uint4 rv = g1v[nc * 4 + q];
        const __half2* hp = (const __half2*)&rv;
#pragma unroll
        for (int m2 = 0; m2 < 4; ++m2) {
            float2 f = __half22float2(hp[m2]);
            acc[2 * m2] = f.x;
            acc[2 * m2 + 1] = f.y;
        }
    }
    for (int base = 0; base < ne; base += 16) {
        int sv[4];
#pragma unroll
        for (int c = 0; c < 4; ++c)
            sv[c] = (base + 4 * c + q < ne) ? col[rs + base + 4 * c + q] : 0;
        int idx[16];
#pragma unroll
        for (int c = 0; c < 4; ++c)
#pragma unroll
            for (int u = 0; u < 4; ++u)
                idx[4 * c + u] = min(__shfl(sv[c], u, 4), N - 1);
        uint4 rv[16];
#pragma unroll
        for (int u = 0; u < 16; ++u) rv[u] = g1v[idx[u] * 4 + q];
#pragma unroll
        for (int u = 0; u < 16; ++u) {
            float wt = (base + u < ne) ? 1.f : 0.f;
            const __half2* hp = (const __half2*)&rv[u];
#pragma unroll
            for (int m2 = 0; m2 < 4; ++m2) {
                float2 f = __half22float2(hp[m2]);
                acc[2 * m2]     = fmaf(wt, f.x, acc[2 * m2]);
                acc[2 * m2 + 1] = fmaf(wt, f.y, acc[2 * m2 + 1]);
            }
        }
    }
    {
        const float dis = rsqrtf((float)(ne + 1));
#pragma unroll
        for (int u = 0; u < 8; ++u) {
            float v = (node < N) ? (acc[u] * dis + b1[q * 8 + u]) : 0.f;
            h1s[nloc * 33 + q * 8 + u] = v > 0.f ? v : 0.f;
        }
    }
    __syncthreads();
    const int n2 = t >> 2, jq = (t & 3) * 4;
    const int node2 = blockIdx.x * 64 + n2;
    if (node2 < N) {
        float a0 = 0.f, a1 = 0.f, a2 = 0.f, a3 = 0.f;
        const float* hr = h1s + n2 * 33;
#pragma unroll
        for (int k = 0; k < 32; ++k) {
            float h = hr[k];
            a0 = fmaf(h, w2t[k * 17 + jq + 0], a0);
            a1 = fmaf(h, w2t[k * 17 + jq + 1], a1);
            a2 = fmaf(h, w2t[k * 17 + jq + 2], a2);
            a3 = fmaf(h, w2t[k * 17 + jq + 3], a3);
        }
        const float dis2 = rsqrtf((float)(deg[node2] + 1));
        __half2* g2p = (__half2*)(g2h + node2 * 16 + jq);
        g2p[0] = __floats2half2_rn(a0 * dis2, a1 * dis2);
        g2p[1] = __floats2half2_rn(a2 * dis2, a3 * dis2);
    }
}

// ---------------- gather layer 2 + FUSED LSTM + output head ----------------
// 128 nodes/block, 2 lanes/node. After gather, h2 goes to an LDS tile and
// threads 0..127 each run the LSTM+head for one node (no h2 global round-trip,
// no separate k_final launch).
__global__ __launch_bounds__(256) void k_gather2(
        const int* __restrict__ row_start, const int* __restrict__ deg,
        const int* __restrict__ col, const __half* __restrict__ g2h,
        const float* __restrict__ b2,
        const float* __restrict__ w_ih, const float* __restrict__ b_ih,
        const float* __restrict__ b_hh, const float* __restrict__ W_out,
        const float* __restrict__ b_out, float* __restrict__ out) {
    __shared__ float h2s[128 * 17];  // 8.7 KB, pad 17
    __shared__ float wih[512];
    __shared__ float bias[32];
    __shared__ float wout[8];
    __shared__ float bo;
    const int t = threadIdx.x;
    for (int idx = t; idx < 512; idx += 256) wih[idx] = w_ih[idx];
    if (t < 32) bias[t] = b_ih[t] + b_hh[t];
    if (t < 8)  wout[t] = W_out[t];
    if (t == 0) bo = b_out[0];

    const int lane = t & 63, w = t >> 6;
    const int q = lane & 1;
    const int nloc = w * 32 + (lane >> 1);
    const int node = blockIdx.x * 128 + nloc;
    const int nc = node < N ? node : N - 1;
    const int rs = row_start[nc];
    const int ne = (node < N) ? deg[nc] : 0;
    const uint4* g2v = (const uint4*)g2h;

    float acc[8];
    {
        uint4 rv = g2v[nc * 2 + q];
        const __half2* hp = (const __half2*)&rv;
#pragma unroll
        for (int m2 = 0; m2 < 4; ++m2) {
            float2 f = __half22float2(hp[m2]);
            acc[2 * m2] = f.x;
            acc[2 * m2 + 1] = f.y;
        }
    }
    for (int base = 0; base < ne; base += 16) {
        int sv[8];
#pragma unroll
        for (int c = 0; c < 8; ++c)
            sv[c] = (base + 2 * c + q < ne) ? col[rs + base + 2 * c + q] : 0;
        int idx[16];
#pragma unroll
        for (int c = 0; c < 8; ++c) {
            idx[2 * c]     = min(__shfl(sv[c], 0, 2), N - 1);
            idx[2 * c + 1] = min(__shfl(sv[c], 1, 2), N - 1);
        }
        uint4 rv[16];
#pragma unroll
        for (int u = 0; u < 16; ++u) rv[u] = g2v[idx[u] * 2 + q];
#pragma unroll
        for (int u = 0; u < 16; ++u) {
            float wt = (base + u < ne) ? 1.f : 0.f;
            const __half2* hp = (const __half2*)&rv[u];
#pragma unroll
            for (int m2 = 0; m2 < 4; ++m2) {
                float2 f = __half22float2(hp[m2]);
                acc[2 * m2]     = fmaf(wt, f.x, acc[2 * m2]);
                acc[2 * m2 + 1] = fmaf(wt, f.y, acc[2 * m2 + 1]);
            }
        }
    }
    {   // h2 -> LDS tile (zeros for tail nodes)
        const float dis = rsqrtf((float)(ne + 1));
#pragma unroll
        for (int u = 0; u < 8; ++u) {
            float v = (node < N) ? (acc[u] * dis + b2[q * 8 + u]) : 0.f;
            h2s[nloc * 17 + q * 8 + u] = v > 0.f ? v : 0.f;
        }
    }
    __syncthreads();
    // fused LSTM + head: threads 0..127, one node each
    if (t < 128) {
        const int node2 = blockIdx.x * 128 + t;
        if (node2 < N) {
            const float* h2 = h2s + t * 17;
            float oacc = 0.f;
#pragma unroll
            for (int g = 0; g < 8; ++g) {
                float gi = bias[g], gg = bias[16 + g], go = bias[24 + g];
#pragma unroll
                for (int k = 0; k < 16; ++k) {
                    gi = fmaf(h2[k], wih[g * 16 + k], gi);
                    gg = fmaf(h2[k], wih[(16 + g) * 16 + k], gg);
                    go = fmaf(h2[k], wih[(24 + g) * 16 + k], go);
                }
                float c  = (1.f / (1.f + expf(-gi))) * tanhf(gg);
                float hh = (1.f / (1.f + expf(-go))) * tanhf(c);
                oacc = fmaf(hh, wout[g], oacc);
            }
            out[node2] = oacc + bo;
        }
    }
}

extern "C" void kernel_launch(void* const* d_in, const int* in_sizes, int n_in,
                              void* d_out, int out_size, void* d_ws, size_t ws_size,
                              hipStream_t stream) {
    const float* x     = (const float*)d_in[0];
    const int*   ei    = (const int*)d_in[1];
    const float* W1    = (const float*)d_in[2];
    const float* b1    = (const float*)d_in[3];
    const float* W2    = (const float*)d_in[4];
    const float* b2    = (const float*)d_in[5];
    const float* w_ih  = (const float*)d_in[6];
    // d_in[7] = w_hh: unused (h0 = 0)
    const float* b_ih  = (const float*)d_in[8];
    const float* b_hh  = (const float*)d_in[9];
    const float* W_out = (const float*)d_in[10];
    const float* b_out = (const float*)d_in[11];
    float* out = (float*)d_out;

    const int E = in_sizes[1] / 2;
    const int* src = ei;
    const int* dst = ei + E;
    const int BP = (E + CHUNK - 1) / CHUNK;

    // workspace (4 B units); disjoint regions, 16 B alignment maintained
    int* col       = (int*)d_ws;                      // COLCAP
    int* deg       = col + COLCAP;                    // N
    int* row_start = deg + N;                         // N
    int* gcur      = row_start + N;                   // 784
    int* base2     = gcur + 784;
    __half* g1h    = (__half*)base2;                  // N*32 halves = N*16 ints
    __half* g2h    = (__half*)(base2 + (size_t)N * 16);   // N*16 halves = N*8 ints

    k_init   <<<1,               1024, 0, stream>>>(gcur);
    k_part   <<<BP,              1024, 0, stream>>>(src, dst, gcur, col, E);
    k_sort   <<<NBUCK,           1024, 0, stream>>>(gcur, col, deg, row_start);
    k_xw1    <<<N / 32,          256,  0, stream>>>(x, W1, deg, g1h);
    k_gather1<<<(N + 63) / 64,   256,  0, stream>>>(row_start, deg, col, g1h, b1, W2, g2h);
    k_gather2<<<(N + 127) / 128, 256,  0, stream>>>(row_start, deg, col, g2h, b2,
                                                    w_ih, b_ih, b_hh, W_out, b_out, out);
}

// Round 13
// 257.937 us; speedup vs baseline: 1.0326x; 1.0326x over previous
//
#include <hip/hip_runtime.h>
#include <hip/hip_fp16.h>
#include <math.h>

static constexpr int N = 100000;
static constexpr int SHIFT = 7;                        // 128 nodes / bucket
static constexpr int BUCKN = 1 << SHIFT;               // 128
static constexpr int NBUCK = (N + BUCKN - 1) >> SHIFT; // 782
static constexpr int CHUNK = 16384;                    // edges per partition block
static constexpr int STRIDE = 5120;                    // per-bucket col capacity (16 sigma)
static constexpr int COLCAP = NBUCK * STRIDE;

// ---------------- init per-bucket cursors ----------------
__global__ __launch_bounds__(1024) void k_init(int* __restrict__ gcur) {
    int b = threadIdx.x;
    if (b < NBUCK) gcur[b] = b * STRIDE;
}

// ---------------- partition edges into fixed-stride bucket regions ----------------
// 1024 threads, NO LDS stash, CHUNK=16384 -> ~21-edge (~84 B) runs, 6.4 KB LDS.
// (Round-12 config: left top-5.)
__global__ __launch_bounds__(1024) void k_part(const int* __restrict__ src,
                                               const int* __restrict__ dst,
                                               int* __restrict__ gcur,
                                               int* __restrict__ col, int E) {
    __shared__ int hl[NBUCK];
    __shared__ int cur[NBUCK];
    const int t = threadIdx.x, b = blockIdx.x;
    if (t < NBUCK) hl[t] = 0;    // 1024 >= NBUCK=782: single-shot OK
    __syncthreads();
    const int e0 = b * CHUNK;
    const int m = min(CHUNK, E - e0);
    for (int i = t; i < m; i += 1024) atomicAdd(&hl[dst[e0 + i] >> SHIFT], 1);
    __syncthreads();
    if (t < NBUCK) cur[t] = atomicAdd(&gcur[t], hl[t]);   // reserve run
    __syncthreads();
    for (int i = t; i < m; i += 1024) {
        int d = dst[e0 + i];
        int pos = atomicAdd(&cur[d >> SHIFT], 1);
        pos = min(max(pos, 0), COLCAP - 1);               // safety clamp (no-op)
        col[pos] = (src[e0 + i] & 0x1FFFF) | ((d & (BUCKN - 1)) << 17);
    }
}

// ---------------- in-bucket counting sort -> per-node CSR (in place) ----------------
__global__ __launch_bounds__(1024) void k_sort(const int* __restrict__ gcur,
                                               int* __restrict__ col,
                                               int* __restrict__ deg,
                                               int* __restrict__ row_start) {
    __shared__ int es[STRIDE];
    __shared__ int cnt[BUCKN];
    __shared__ int cur[BUCKN];
    const int t = threadIdx.x, buck = blockIdx.x;
    const int s0 = buck * STRIDE;
    int n = gcur[buck] - s0;
    n = max(0, min(n, STRIDE));
    if (t < BUCKN) cnt[t] = 0;
    __syncthreads();
    for (int i = t; i < n; i += 1024) {
        int p = col[s0 + i];
        es[i] = p;
        atomicAdd(&cnt[(p >> 17) & (BUCKN - 1)], 1);
    }
    __syncthreads();
    if (t < BUCKN) cur[t] = cnt[t];
    __syncthreads();
    for (int off = 1; off < BUCKN; off <<= 1) {
        int v = (t < BUCKN && t >= off) ? cur[t - off] : 0;
        __syncthreads();
        if (t < BUCKN) cur[t] += v;
        __syncthreads();
    }
    if (t < BUCKN) {
        int excl = cur[t] - cnt[t];
        int node = buck * BUCKN + t;
        if (node < N) {
            deg[node] = cnt[t];
            row_start[node] = s0 + excl;
        }
        cur[t] = excl;
    }
    __syncthreads();
    for (int i = t; i < n; i += 1024) {
        int p = es[i];
        int pos = atomicAdd(&cur[(p >> 17) & (BUCKN - 1)], 1);
        pos = min(max(pos, 0), STRIDE - 1);
        col[s0 + pos] = p & 0x1FFFF;
    }
}

// ---------------- layer 1 transform: g1h = fp16( dis * (x @ W1^T) ) ----------------
__global__ __launch_bounds__(256) void k_xw1(
        const float* __restrict__ x, const float* __restrict__ W1,
        const int* __restrict__ deg, __half* __restrict__ g1h) {
    __shared__ float4 wtv[32 * 33];   // [kb][j] quad of W1[j][4kb..4kb+3], pad 33
    __shared__ float4 xsv[1024];      // 32 nodes x 32 k-quads
    const int t = threadIdx.x;
    const float4* W1v = (const float4*)W1;
    for (int idx = t; idx < 1024; idx += 256) {
        int j = idx >> 5, kb = idx & 31;
        wtv[kb * 33 + j] = W1v[idx];
    }
    const float4* x4 = (const float4*)x + (size_t)blockIdx.x * 1024;
    for (int idx = t; idx < 1024; idx += 256) xsv[idx] = x4[idx];
    __syncthreads();

    const int j = t & 31, ng = t >> 5;
    float a0 = 0.f, a1 = 0.f, a2 = 0.f, a3 = 0.f;
#pragma unroll 4
    for (int kb = 0; kb < 32; ++kb) {
        float4 w = wtv[kb * 33 + j];
        float4 x0 = xsv[(4 * ng + 0) * 32 + kb];
        float4 x1 = xsv[(4 * ng + 1) * 32 + kb];
        float4 x2 = xsv[(4 * ng + 2) * 32 + kb];
        float4 x3 = xsv[(4 * ng + 3) * 32 + kb];
        a0 = fmaf(w.x, x0.x, fmaf(w.y, x0.y, fmaf(w.z, x0.z, fmaf(w.w, x0.w, a0))));
        a1 = fmaf(w.x, x1.x, fmaf(w.y, x1.y, fmaf(w.z, x1.z, fmaf(w.w, x1.w, a1))));
        a2 = fmaf(w.x, x2.x, fmaf(w.y, x2.y, fmaf(w.z, x2.z, fmaf(w.w, x2.w, a2))));
        a3 = fmaf(w.x, x3.x, fmaf(w.y, x3.y, fmaf(w.z, x3.z, fmaf(w.w, x3.w, a3))));
    }
    const int nb = blockIdx.x * 32 + 4 * ng;
    g1h[(nb + 0) * 32 + j] = __float2half(a0 * rsqrtf((float)(deg[nb + 0] + 1)));
    g1h[(nb + 1) * 32 + j] = __float2half(a1 * rsqrtf((float)(deg[nb + 1] + 1)));
    g1h[(nb + 2) * 32 + j] = __float2half(a2 * rsqrtf((float)(deg[nb + 2] + 1)));
    g1h[(nb + 3) * 32 + j] = __float2half(a3 * rsqrtf((float)(deg[nb + 3] + 1)));
}

// ---------------- gather layer 1 + FUSED layer-2 transform ----------------
// (Lean tail: this fusion keeps VGPR moderate and stays off the top-5.)
__global__ __launch_bounds__(256) void k_gather1(
        const int* __restrict__ row_start, const int* __restrict__ deg,
        const int* __restrict__ col, const __half* __restrict__ g1h,
        const float* __restrict__ b1, const float* __restrict__ W2,
        __half* __restrict__ g2h) {
    __shared__ float h1s[64 * 33];   // 8.4 KB, pad 33
    __shared__ float w2t[32 * 17];   // W2 transposed [k][j], pad 17
    const int t = threadIdx.x;
    for (int idx = t; idx < 512; idx += 256) {
        int j = idx >> 5, k = idx & 31;
        w2t[k * 17 + j] = W2[idx];
    }
    const int lane = t & 63, w = t >> 6;
    const int q = lane & 3;                      // feature octet
    const int nloc = w * 16 + (lane >> 2);
    const int node = blockIdx.x * 64 + nloc;
    const int nc = node < N ? node : N - 1;
    const int rs = row_start[nc];
    const int ne = (node < N) ? deg[nc] : 0;
    const uint4* g1v = (const uint4*)g1h;

    float acc[8];
    {
        uint4 rv = g1v[nc * 4 + q];
        const __half2* hp = (const __half2*)&rv;
#pragma unroll
        for (int m2 = 0; m2 < 4; ++m2) {
            float2 f = __half22float2(hp[m2]);
            acc[2 * m2] = f.x;
            acc[2 * m2 + 1] = f.y;
        }
    }
    for (int base = 0; base < ne; base += 16) {
        int sv[4];
#pragma unroll
        for (int c = 0; c < 4; ++c)
            sv[c] = (base + 4 * c + q < ne) ? col[rs + base + 4 * c + q] : 0;
        int idx[16];
#pragma unroll
        for (int c = 0; c < 4; ++c)
#pragma unroll
            for (int u = 0; u < 4; ++u)
                idx[4 * c + u] = min(__shfl(sv[c], u, 4), N - 1);
        uint4 rv[16];
#pragma unroll
        for (int u = 0; u < 16; ++u) rv[u] = g1v[idx[u] * 4 + q];
#pragma unroll
        for (int u = 0; u < 16; ++u) {
            float wt = (base + u < ne) ? 1.f : 0.f;
            const __half2* hp = (const __half2*)&rv[u];
#pragma unroll
            for (int m2 = 0; m2 < 4; ++m2) {
                float2 f = __half22float2(hp[m2]);
                acc[2 * m2]     = fmaf(wt, f.x, acc[2 * m2]);
                acc[2 * m2 + 1] = fmaf(wt, f.y, acc[2 * m2 + 1]);
            }
        }
    }
    {
        const float dis = rsqrtf((float)(ne + 1));
#pragma unroll
        for (int u = 0; u < 8; ++u) {
            float v = (node < N) ? (acc[u] * dis + b1[q * 8 + u]) : 0.f;
            h1s[nloc * 33 + q * 8 + u] = v > 0.f ? v : 0.f;
        }
    }
    __syncthreads();
    const int n2 = t >> 2, jq = (t & 3) * 4;
    const int node2 = blockIdx.x * 64 + n2;
    if (node2 < N) {
        float a0 = 0.f, a1 = 0.f, a2 = 0.f, a3 = 0.f;
        const float* hr = h1s + n2 * 33;
#pragma unroll
        for (int k = 0; k < 32; ++k) {
            float h = hr[k];
            a0 = fmaf(h, w2t[k * 17 + jq + 0], a0);
            a1 = fmaf(h, w2t[k * 17 + jq + 1], a1);
            a2 = fmaf(h, w2t[k * 17 + jq + 2], a2);
            a3 = fmaf(h, w2t[k * 17 + jq + 3], a3);
        }
        const float dis2 = rsqrtf((float)(deg[node2] + 1));
        __half2* g2p = (__half2*)(g2h + node2 * 16 + jq);
        g2p[0] = __floats2half2_rn(a0 * dis2, a1 * dis2);
        g2p[1] = __floats2half2_rn(a2 * dis2, a3 * dis2);
    }
}

// ---------------- gather layer 2 (UNFUSED — lean, latency-bound needs occupancy) ----------------
// Round-12 fused LSTM here: VGPR 40->132, occupancy 7%, 3x slower. Keep split.
__global__ __launch_bounds__(256) void k_gather2(
        const int* __restrict__ row_start, const int* __restrict__ deg,
        const int* __restrict__ col, const __half* __restrict__ g2h,
        const float* __restrict__ b2, float* __restrict__ h2) {
    const int t = threadIdx.x;
    const int lane = t & 63, w = t >> 6;
    const int q = lane & 1;
    const int node = blockIdx.x * 128 + w * 32 + (lane >> 1);
    const int nc = node < N ? node : N - 1;
    const int rs = row_start[nc];
    const int ne = (node < N) ? deg[nc] : 0;
    const uint4* g2v = (const uint4*)g2h;

    float acc[8];
    {
        uint4 rv = g2v[nc * 2 + q];
        const __half2* hp = (const __half2*)&rv;
#pragma unroll
        for (int m2 = 0; m2 < 4; ++m2) {
            float2 f = __half22float2(hp[m2]);
            acc[2 * m2] = f.x;
            acc[2 * m2 + 1] = f.y;
        }
    }
    for (int base = 0; base < ne; base += 16) {
        int sv[8];
#pragma unroll
        for (int c = 0; c < 8; ++c)
            sv[c] = (base + 2 * c + q < ne) ? col[rs + base + 2 * c + q] : 0;
        int idx[16];
#pragma unroll
        for (int c = 0; c < 8; ++c) {
            idx[2 * c]     = min(__shfl(sv[c], 0, 2), N - 1);
            idx[2 * c + 1] = min(__shfl(sv[c], 1, 2), N - 1);
        }
        uint4 rv[16];
#pragma unroll
        for (int u = 0; u < 16; ++u) rv[u] = g2v[idx[u] * 2 + q];
#pragma unroll
        for (int u = 0; u < 16; ++u) {
            float wt = (base + u < ne) ? 1.f : 0.f;
            const __half2* hp = (const __half2*)&rv[u];
#pragma unroll
            for (int m2 = 0; m2 < 4; ++m2) {
                float2 f = __half22float2(hp[m2]);
                acc[2 * m2]     = fmaf(wt, f.x, acc[2 * m2]);
                acc[2 * m2 + 1] = fmaf(wt, f.y, acc[2 * m2 + 1]);
            }
        }
    }
    if (node < N) {
        const float dis = rsqrtf((float)(ne + 1));
        float4* h2v = (float4*)h2;
#pragma unroll
        for (int h = 0; h < 2; ++h) {
            float4 o;
            float v0 = acc[4 * h + 0] * dis + b2[q * 8 + 4 * h + 0];
            float v1 = acc[4 * h + 1] * dis + b2[q * 8 + 4 * h + 1];
            float v2 = acc[4 * h + 2] * dis + b2[q * 8 + 4 * h + 2];
            float v3 = acc[4 * h + 3] * dis + b2[q * 8 + 4 * h + 3];
            o.x = v0 > 0.f ? v0 : 0.f;
            o.y = v1 > 0.f ? v1 : 0.f;
            o.z = v2 > 0.f ? v2 : 0.f;
            o.w = v3 > 0.f ? v3 : 0.f;
            h2v[node * 4 + q * 2 + h] = o;
        }
    }
}

// ---------------- LSTM (h0=c0=0) + output head ----------------
__global__ __launch_bounds__(256) void k_final(
        const float* __restrict__ h2g,
        const float* __restrict__ w_ih, const float* __restrict__ b_ih,
        const float* __restrict__ b_hh, const float* __restrict__ W_out,
        const float* __restrict__ b_out, float* __restrict__ out) {
    __shared__ float wih[512];
    __shared__ float bias[32];
    __shared__ float wout[8];
    __shared__ float bo;
    const int t = threadIdx.x;
    for (int idx = t; idx < 512; idx += 256) wih[idx] = w_ih[idx];
    if (t < 32) bias[t] = b_ih[t] + b_hh[t];
    if (t < 8)  wout[t] = W_out[t];
    if (t == 0) bo = b_out[0];
    __syncthreads();

    const int i = blockIdx.x * 256 + t;
    if (i >= N) return;
    float h2[16];
    const float4* a4 = (const float4*)(h2g + (size_t)i * 16);
#pragma unroll
    for (int q = 0; q < 4; ++q) {
        float4 v = a4[q];
        h2[q * 4 + 0] = v.x; h2[q * 4 + 1] = v.y;
        h2[q * 4 + 2] = v.z; h2[q * 4 + 3] = v.w;
    }
    float oacc = 0.f;
#pragma unroll
    for (int q = 0; q < 8; ++q) {
        float gi = bias[q], gg = bias[16 + q], go = bias[24 + q];
#pragma unroll
        for (int k = 0; k < 16; ++k) {
            gi = fmaf(h2[k], wih[q * 16 + k], gi);
            gg = fmaf(h2[k], wih[(16 + q) * 16 + k], gg);
            go = fmaf(h2[k], wih[(24 + q) * 16 + k], go);
        }
        float c  = (1.f / (1.f + expf(-gi))) * tanhf(gg);
        float hh = (1.f / (1.f + expf(-go))) * tanhf(c);
        oacc = fmaf(hh, wout[q], oacc);
    }
    out[i] = oacc + bo;
}

extern "C" void kernel_launch(void* const* d_in, const int* in_sizes, int n_in,
                              void* d_out, int out_size, void* d_ws, size_t ws_size,
                              hipStream_t stream) {
    const float* x     = (const float*)d_in[0];
    const int*   ei    = (const int*)d_in[1];
    const float* W1    = (const float*)d_in[2];
    const float* b1    = (const float*)d_in[3];
    const float* W2    = (const float*)d_in[4];
    const float* b2    = (const float*)d_in[5];
    const float* w_ih  = (const float*)d_in[6];
    // d_in[7] = w_hh: unused (h0 = 0)
    const float* b_ih  = (const float*)d_in[8];
    const float* b_hh  = (const float*)d_in[9];
    const float* W_out = (const float*)d_in[10];
    const float* b_out = (const float*)d_in[11];
    float* out = (float*)d_out;

    const int E = in_sizes[1] / 2;
    const int* src = ei;
    const int* dst = ei + E;
    const int BP = (E + CHUNK - 1) / CHUNK;

    // workspace (4 B units); disjoint regions, 16 B alignment maintained
    int* col       = (int*)d_ws;                      // COLCAP
    int* deg       = col + COLCAP;                    // N
    int* row_start = deg + N;                         // N
    int* gcur      = row_start + N;                   // 784
    int* base2     = gcur + 784;
    __half* g1h    = (__half*)base2;                      // N*32 halves = N*16 ints
    __half* g2h    = (__half*)(base2 + (size_t)N * 16);   // N*16 halves = N*8 ints
    float* h2      = (float*)(base2 + (size_t)N * 24);    // N*16 floats

    k_init   <<<1,               1024, 0, stream>>>(gcur);
    k_part   <<<BP,              1024, 0, stream>>>(src, dst, gcur, col, E);
    k_sort   <<<NBUCK,           1024, 0, stream>>>(gcur, col, deg, row_start);
    k_xw1    <<<N / 32,          256,  0, stream>>>(x, W1, deg, g1h);
    k_gather1<<<(N + 63) / 64,   256,  0, stream>>>(row_start, deg, col, g1h, b1, W2, g2h);
    k_gather2<<<(N + 127) / 128, 256,  0, stream>>>(row_start, deg, col, g2h, b2, h2);
    k_final  <<<(N + 255) / 256, 256,  0, stream>>>(h2, w_ih, b_ih, b_hh, W_out, b_out, out);
}